// Round 1
// baseline (368.825 us; speedup 1.0000x reference)
//
#include <hip/hip_runtime.h>
#include <math.h>

#define B_ 4
#define K_ 4
#define D_ 96
#define L_ 2048
#define N_ 16
#define R_ 6
#define C_ 38          // R + 2N
#define CHUNK 8        // L_ / 256

__device__ __forceinline__ float softplus_f(float x) {
    // jax.nn.softplus = logaddexp(x, 0) = max(x,0) + log1p(exp(-|x|))
    return fmaxf(x, 0.f) + log1pf(expf(-fabsf(x)));
}

// Kernel 1: x_dbl projection + dt projection + softplus.
// grid (B*K, L/128), block 128. One thread per (b,k,l).
__global__ __launch_bounds__(128) void proj_kernel(
    const float* __restrict__ xs, const float* __restrict__ xpw,
    const float* __restrict__ dtw, const float* __restrict__ dtb,
    float* __restrict__ delta_ws, float* __restrict__ B_ws, float* __restrict__ C_ws)
{
    __shared__ float sW[C_ * D_];    // 3648 floats
    __shared__ float sDtw[D_ * R_];  // 576
    __shared__ float sBias[D_];      // 96
    const int bk = blockIdx.x;
    const int k = bk % K_;
    const int tid = threadIdx.x;
    for (int i = tid; i < C_ * D_; i += 128) sW[i] = xpw[k * C_ * D_ + i];
    for (int i = tid; i < D_ * R_; i += 128) sDtw[i] = dtw[k * D_ * R_ + i];
    if (tid < D_) sBias[tid] = dtb[k * D_ + tid];
    __syncthreads();

    const int l = blockIdx.y * 128 + tid;
    const float* xsp = xs + (size_t)bk * (D_ * L_) + l;

    float acc[C_];
#pragma unroll
    for (int c = 0; c < C_; ++c) acc[c] = 0.f;

    for (int d = 0; d < D_; d += 4) {
        const float x0 = xsp[(d + 0) * L_];
        const float x1 = xsp[(d + 1) * L_];
        const float x2 = xsp[(d + 2) * L_];
        const float x3 = xsp[(d + 3) * L_];
#pragma unroll
        for (int c = 0; c < C_; ++c) {
            const float4 w = *(const float4*)&sW[c * D_ + d];  // 16B-aligned: 96%4==0
            acc[c] += x0 * w.x + x1 * w.y + x2 * w.z + x3 * w.w;
        }
    }

    float* Bp = B_ws + (size_t)bk * (N_ * L_) + l;
    float* Cp = C_ws + (size_t)bk * (N_ * L_) + l;
#pragma unroll
    for (int n = 0; n < N_; ++n) {
        Bp[n * L_] = acc[R_ + n];
        Cp[n * L_] = acc[R_ + N_ + n];
    }

    float* Dp = delta_ws + (size_t)bk * (D_ * L_) + l;
    for (int d = 0; d < D_; ++d) {
        float v = sBias[d];
#pragma unroll
        for (int r = 0; r < R_; ++r) v += acc[r] * sDtw[d * R_ + r];
        Dp[d * L_] = softplus_f(v);
    }
}

// Kernel 2: chunked parallel scan. grid = B*K*D blocks, 256 threads.
// Thread t owns l in [t*8, t*8+8). combine(e1,e2) = (a1*a2, a2*b1+b2).
__global__ __launch_bounds__(256) void scan_kernel(
    const float* __restrict__ xs, const float* __restrict__ A_logs,
    const float* __restrict__ Ds,
    const float* __restrict__ delta_ws, const float* __restrict__ B_ws,
    const float* __restrict__ C_ws, float* __restrict__ out)
{
    __shared__ float sdl[L_];
    __shared__ float sx[L_];
    __shared__ float sAw[4][N_];
    __shared__ float sBw[4][N_];

    const int bkd = blockIdx.x;
    const int d = bkd % D_;
    const int bk = bkd / D_;
    const int k = bk % K_;
    const int tid = threadIdx.x;
    const int lane = tid & 63;
    const int wave = tid >> 6;

    // stage delta and xs rows (coalesced)
    const float* dlp = delta_ws + (size_t)bkd * L_;
    const float* xp = xs + (size_t)bkd * L_;
#pragma unroll
    for (int i = 0; i < L_ / 256; ++i) {
        sdl[tid + i * 256] = dlp[tid + i * 256];
        sx[tid + i * 256] = xp[tid + i * 256];
    }

    float A[N_];
    const float* Ap = A_logs + (size_t)(k * D_ + d) * N_;
#pragma unroll
    for (int n = 0; n < N_; ++n) A[n] = -expf(Ap[n]);
    const float Dval = Ds[k * D_ + d];
    __syncthreads();

    const float* Bp = B_ws + (size_t)bk * (N_ * L_);
    const float* Cp = C_ws + (size_t)bk * (N_ * L_);
    const int l0 = tid * CHUNK;

    // Phase 1: per-chunk aggregate
    float a[N_], b[N_];
#pragma unroll
    for (int n = 0; n < N_; ++n) { a[n] = 1.f; b[n] = 0.f; }
    for (int i = 0; i < CHUNK; ++i) {
        const int l = l0 + i;
        const float dl = sdl[l];
        const float dlx = dl * sx[l];
#pragma unroll
        for (int n = 0; n < N_; ++n) {
            const float dA = expf(dl * A[n]);
            b[n] = dA * b[n] + dlx * Bp[n * L_ + l];  // b must update before a
            a[n] *= dA;
        }
    }

    // Phase 2a: wave-level inclusive Hillis-Steele scan
#pragma unroll
    for (int off = 1; off < 64; off <<= 1) {
#pragma unroll
        for (int n = 0; n < N_; ++n) {
            const float pa = __shfl_up(a[n], off, 64);
            const float pb = __shfl_up(b[n], off, 64);
            if (lane >= off) {
                b[n] = a[n] * pb + b[n];
                a[n] = a[n] * pa;
            }
        }
    }
    // Phase 2b: cross-wave fixup via LDS
    if (lane == 63) {
#pragma unroll
        for (int n = 0; n < N_; ++n) { sAw[wave][n] = a[n]; sBw[wave][n] = b[n]; }
    }
    __syncthreads();

    // h at chunk start = b-component of combine(wave_prefix, lane_exclusive)
    float h[N_];
#pragma unroll
    for (int n = 0; n < N_; ++n) {
        float ae = __shfl_up(a[n], 1, 64);
        float be = __shfl_up(b[n], 1, 64);
        if (lane == 0) { ae = 1.f; be = 0.f; }
        float wb = 0.f;
        for (int w = 0; w < wave; ++w) wb = sAw[w][n] * wb + sBw[w][n];
        h[n] = ae * wb + be;
    }

    // Phase 3: re-run chunk with true initial state, emit y
    float* op = out + (size_t)bkd * L_;
    for (int i = 0; i < CHUNK; ++i) {
        const int l = l0 + i;
        const float dl = sdl[l];
        const float x = sx[l];
        const float dlx = dl * x;
        float y = Dval * x;
#pragma unroll
        for (int n = 0; n < N_; ++n) {
            const float dA = expf(dl * A[n]);
            h[n] = dA * h[n] + dlx * Bp[n * L_ + l];
            y += h[n] * Cp[n * L_ + l];
        }
        op[l] = y;
    }
}

extern "C" void kernel_launch(void* const* d_in, const int* in_sizes, int n_in,
                              void* d_out, int out_size, void* d_ws, size_t ws_size,
                              hipStream_t stream) {
    const float* xs = (const float*)d_in[0];       // (B,K,D,L)
    const float* A_logs = (const float*)d_in[1];   // (K*D, N)
    const float* Ds = (const float*)d_in[2];       // (K*D,)
    const float* dtw = (const float*)d_in[3];      // (K,D,R)
    const float* dtb = (const float*)d_in[4];      // (K,D)
    const float* xpw = (const float*)d_in[5];      // (K,C,D)
    float* out = (float*)d_out;                    // (B,K,D,L) fp32

    float* ws = (float*)d_ws;
    float* delta_ws = ws;                            // B*K*D*L = 3145728
    float* B_ws = delta_ws + (size_t)B_ * K_ * D_ * L_;  // B*K*N*L = 524288
    float* C_ws = B_ws + (size_t)B_ * K_ * N_ * L_;      // 524288  (16 MB total)

    proj_kernel<<<dim3(B_ * K_, L_ / 128), 128, 0, stream>>>(
        xs, xpw, dtw, dtb, delta_ws, B_ws, C_ws);
    scan_kernel<<<B_ * K_ * D_, 256, 0, stream>>>(
        xs, A_logs, Ds, delta_ws, B_ws, C_ws, out);
}

// Round 2
// 209.263 us; speedup vs baseline: 1.7625x; 1.7625x over previous
//
#include <hip/hip_runtime.h>
#include <math.h>

#define B_ 4
#define K_ 4
#define D_ 96
#define L_ 2048
#define N_ 16
#define R_ 6
#define C_ 38          // R + 2N

__device__ __forceinline__ float softplus_f(float x) {
    // jax.nn.softplus = max(x,0) + log1p(exp(-|x|))
    return fmaxf(x, 0.f) + log1pf(expf(-fabsf(x)));
}

// ---------------------------------------------------------------------------
// K1a: dts rows (c = 0..5). grid (B*K, 2), block 256. Thread owns 4 l's
// (strided by 256 for coalescing). Writes dts_ws in (bk, r, l) layout.
// ---------------------------------------------------------------------------
__global__ __launch_bounds__(256) void proj_dts_kernel(
    const float* __restrict__ xs, const float* __restrict__ xpw,
    float* __restrict__ dts_ws)
{
    __shared__ float sW[R_ * D_];
    const int bk = blockIdx.x;
    const int k = bk & 3;
    const int tid = threadIdx.x;
    for (int i = tid; i < R_ * D_; i += 256)
        sW[i] = xpw[(k * C_ + i / D_) * D_ + (i % D_)];
    __syncthreads();

    const int l0 = blockIdx.y * 1024 + tid;
    const float* X = xs + (size_t)bk * D_ * L_;

    float acc[R_][4];
#pragma unroll
    for (int r = 0; r < R_; ++r)
#pragma unroll
        for (int j = 0; j < 4; ++j) acc[r][j] = 0.f;

#pragma unroll 4
    for (int d = 0; d < D_; ++d) {
        float xv[4];
#pragma unroll
        for (int j = 0; j < 4; ++j) xv[j] = X[d * L_ + l0 + j * 256];
#pragma unroll
        for (int r = 0; r < R_; ++r)
#pragma unroll
            for (int j = 0; j < 4; ++j)
                acc[r][j] = fmaf(sW[r * D_ + d], xv[j], acc[r][j]);
    }

#pragma unroll
    for (int r = 0; r < R_; ++r)
#pragma unroll
        for (int j = 0; j < 4; ++j)
            dts_ws[((size_t)bk * R_ + r) * L_ + l0 + j * 256] = acc[r][j];
}

// ---------------------------------------------------------------------------
// K1b: B/C rows in TRANSPOSED (bk, l, n) layout. grid (B*K, 2, 8), block 256.
// gz 0..3 -> B n-groups of 4; gz 4..7 -> C n-groups of 4.
// ---------------------------------------------------------------------------
__global__ __launch_bounds__(256) void proj_bc_kernel(
    const float* __restrict__ xs, const float* __restrict__ xpw,
    float* __restrict__ Bt, float* __restrict__ Ct)
{
    __shared__ float sW[4 * D_];
    const int bk = blockIdx.x;
    const int k = bk & 3;
    const int gz = blockIdx.z;
    const int c0 = R_ + gz * 4;
    const int tid = threadIdx.x;
    for (int i = tid; i < 4 * D_; i += 256)
        sW[i] = xpw[(k * C_ + c0 + i / D_) * D_ + (i % D_)];
    __syncthreads();

    const int l0 = blockIdx.y * 1024 + tid;
    const float* X = xs + (size_t)bk * D_ * L_;

    float acc[4][4];
#pragma unroll
    for (int ct = 0; ct < 4; ++ct)
#pragma unroll
        for (int j = 0; j < 4; ++j) acc[ct][j] = 0.f;

#pragma unroll 4
    for (int d = 0; d < D_; ++d) {
        float xv[4];
#pragma unroll
        for (int j = 0; j < 4; ++j) xv[j] = X[d * L_ + l0 + j * 256];
#pragma unroll
        for (int ct = 0; ct < 4; ++ct)
#pragma unroll
            for (int j = 0; j < 4; ++j)
                acc[ct][j] = fmaf(sW[ct * D_ + d], xv[j], acc[ct][j]);
    }

    float* dst = (gz < 4) ? Bt : Ct;
    const int n0 = (gz & 3) * 4;
#pragma unroll
    for (int j = 0; j < 4; ++j) {
        const int l = l0 + j * 256;
        *(float4*)&dst[((size_t)bk * L_ + l) * N_ + n0] =
            make_float4(acc[0][j], acc[1][j], acc[2][j], acc[3][j]);
    }
}

// ---------------------------------------------------------------------------
// K2: chunked parallel scan. grid B*K*D, block 256; thread owns 8 contiguous
// l. All per-thread data in registers; B/C read as contiguous 64B per step.
// Delta computed in-kernel from dts rows (saves the delta ws round trip).
// ---------------------------------------------------------------------------
__global__ __launch_bounds__(256) void scan_kernel(
    const float* __restrict__ xs, const float* __restrict__ A_logs,
    const float* __restrict__ Ds, const float* __restrict__ dtw,
    const float* __restrict__ dtb, const float* __restrict__ dts_ws,
    const float* __restrict__ Bt, const float* __restrict__ Ct,
    float* __restrict__ out)
{
    __shared__ float sAw[4][N_];
    __shared__ float sBw[4][N_];

    const int bkd = blockIdx.x;
    const int d = bkd % D_;
    const int bk = bkd / D_;
    const int k = bk & 3;
    const int kd = k * D_ + d;
    const int tid = threadIdx.x;
    const int lane = tid & 63;
    const int wave = tid >> 6;
    const int l0 = tid * 8;

    // xs chunk -> registers (2x float4, contiguous per thread)
    const float4* xv4 = (const float4*)(xs + (size_t)bkd * L_);
    const float4 xa = xv4[tid * 2], xb = xv4[tid * 2 + 1];
    float x[8] = {xa.x, xa.y, xa.z, xa.w, xb.x, xb.y, xb.z, xb.w};

    // delta chunk: bias + sum_r w2[r]*dts[r][l], then softplus
    float del[8];
    const float bias = dtb[kd];
#pragma unroll
    for (int j = 0; j < 8; ++j) del[j] = bias;
    const float* w2 = dtw + (size_t)kd * R_;
    const float4* dts4 = (const float4*)(dts_ws + (size_t)bk * R_ * L_);
#pragma unroll
    for (int r = 0; r < R_; ++r) {
        const float wr = w2[r];
        const float4 t0 = dts4[r * (L_ / 4) + tid * 2];
        const float4 t1 = dts4[r * (L_ / 4) + tid * 2 + 1];
        del[0] = fmaf(wr, t0.x, del[0]); del[1] = fmaf(wr, t0.y, del[1]);
        del[2] = fmaf(wr, t0.z, del[2]); del[3] = fmaf(wr, t0.w, del[3]);
        del[4] = fmaf(wr, t1.x, del[4]); del[5] = fmaf(wr, t1.y, del[5]);
        del[6] = fmaf(wr, t1.z, del[6]); del[7] = fmaf(wr, t1.w, del[7]);
    }
#pragma unroll
    for (int j = 0; j < 8; ++j) del[j] = softplus_f(del[j]);

    float A[N_];
    const float* Ap = A_logs + (size_t)kd * N_;
#pragma unroll
    for (int n = 0; n < N_; ++n) A[n] = -expf(Ap[n]);
    const float Dval = Ds[kd];

    float dlx[8];
#pragma unroll
    for (int j = 0; j < 8; ++j) dlx[j] = del[j] * x[j];

    const float4* Bv = (const float4*)Bt + ((size_t)bk * L_ + l0) * 4;
    const float4* Cv = (const float4*)Ct + ((size_t)bk * L_ + l0) * 4;

    // Phase 1: per-chunk aggregate (a, b)
    float a[N_], b[N_];
#pragma unroll
    for (int n = 0; n < N_; ++n) { a[n] = 1.f; b[n] = 0.f; }
#pragma unroll
    for (int i = 0; i < 8; ++i) {
        float Bl[N_];
        *(float4*)&Bl[0]  = Bv[i * 4 + 0];
        *(float4*)&Bl[4]  = Bv[i * 4 + 1];
        *(float4*)&Bl[8]  = Bv[i * 4 + 2];
        *(float4*)&Bl[12] = Bv[i * 4 + 3];
        const float dl = del[i], dx = dlx[i];
#pragma unroll
        for (int n = 0; n < N_; ++n) {
            const float dA = __expf(dl * A[n]);
            b[n] = fmaf(dA, b[n], dx * Bl[n]);
            a[n] *= dA;
        }
    }

    // Phase 2a: wave-level inclusive scan (Hillis-Steele)
#pragma unroll
    for (int off = 1; off < 64; off <<= 1) {
#pragma unroll
        for (int n = 0; n < N_; ++n) {
            const float pa = __shfl_up(a[n], off, 64);
            const float pb = __shfl_up(b[n], off, 64);
            if (lane >= off) {
                b[n] = fmaf(a[n], pb, b[n]);
                a[n] *= pa;
            }
        }
    }
    // Phase 2b: cross-wave fixup
    if (lane == 63) {
#pragma unroll
        for (int n = 0; n < N_; ++n) { sAw[wave][n] = a[n]; sBw[wave][n] = b[n]; }
    }
    __syncthreads();

    // h at chunk start = combine(wave_prefix, lane_exclusive).b
    float h[N_];
#pragma unroll
    for (int n = 0; n < N_; ++n) {
        float ae = __shfl_up(a[n], 1, 64);
        float be = __shfl_up(b[n], 1, 64);
        if (lane == 0) { ae = 1.f; be = 0.f; }
        float wb = 0.f;
        for (int w = 0; w < wave; ++w) wb = fmaf(sAw[w][n], wb, sBw[w][n]);
        h[n] = fmaf(ae, wb, be);
    }

    // Phase 3: re-run chunk with true initial state, emit y
    float yv[8];
#pragma unroll
    for (int i = 0; i < 8; ++i) {
        float Bl[N_], Cl[N_];
        *(float4*)&Bl[0]  = Bv[i * 4 + 0];
        *(float4*)&Bl[4]  = Bv[i * 4 + 1];
        *(float4*)&Bl[8]  = Bv[i * 4 + 2];
        *(float4*)&Bl[12] = Bv[i * 4 + 3];
        *(float4*)&Cl[0]  = Cv[i * 4 + 0];
        *(float4*)&Cl[4]  = Cv[i * 4 + 1];
        *(float4*)&Cl[8]  = Cv[i * 4 + 2];
        *(float4*)&Cl[12] = Cv[i * 4 + 3];
        const float dl = del[i], dx = dlx[i];
        float y = Dval * x[i];
#pragma unroll
        for (int n = 0; n < N_; ++n) {
            const float dA = __expf(dl * A[n]);
            h[n] = fmaf(dA, h[n], dx * Bl[n]);
            y = fmaf(h[n], Cl[n], y);
        }
        yv[i] = y;
    }
    float4* ov = (float4*)(out + (size_t)bkd * L_);
    ov[tid * 2]     = make_float4(yv[0], yv[1], yv[2], yv[3]);
    ov[tid * 2 + 1] = make_float4(yv[4], yv[5], yv[6], yv[7]);
}

extern "C" void kernel_launch(void* const* d_in, const int* in_sizes, int n_in,
                              void* d_out, int out_size, void* d_ws, size_t ws_size,
                              hipStream_t stream) {
    const float* xs = (const float*)d_in[0];       // (B,K,D,L)
    const float* A_logs = (const float*)d_in[1];   // (K*D, N)
    const float* Ds = (const float*)d_in[2];       // (K*D,)
    const float* dtw = (const float*)d_in[3];      // (K,D,R)
    const float* dtb = (const float*)d_in[4];      // (K,D)
    const float* xpw = (const float*)d_in[5];      // (K,C,D)
    float* out = (float*)d_out;                    // (B,K,D,L) fp32

    float* ws = (float*)d_ws;
    float* dts_ws = ws;                                   // 16*6*2048   = 196608
    float* Bt = dts_ws + (size_t)B_ * K_ * R_ * L_;       // 16*2048*16  = 524288
    float* Ct = Bt + (size_t)B_ * K_ * L_ * N_;           // 524288  (~5 MB total)

    proj_dts_kernel<<<dim3(B_ * K_, 2), 256, 0, stream>>>(xs, xpw, dts_ws);
    proj_bc_kernel<<<dim3(B_ * K_, 2, 8), 256, 0, stream>>>(xs, xpw, Bt, Ct);
    scan_kernel<<<B_ * K_ * D_, 256, 0, stream>>>(
        xs, A_logs, Ds, dtw, dtb, dts_ws, Bt, Ct, out);
}

// Round 3
// 162.135 us; speedup vs baseline: 2.2748x; 1.2907x over previous
//
#include <hip/hip_runtime.h>
#include <math.h>

#define B_ 4
#define K_ 4
#define D_ 96
#define L_ 2048
#define N_ 16
#define R_ 6
#define C_ 38          // R + 2N

__device__ __forceinline__ float softplus_f(float x) {
    // softplus = max(x,0) + log1p(exp(-|x|)); fast intrinsics are fine:
    // exp(-|x|) in (0,1], so log(1+t) loses no significance.
    return fmaxf(x, 0.f) + __logf(1.f + __expf(-fabsf(x)));
}

// ---------------------------------------------------------------------------
// Proj: one kernel for dts + B + C. grid (B*K, 4, 10), block 256.
//   cg 0..3  -> B n-group cg      (4 rows, c = R + cg*4)
//   cg 4..7  -> C n-group cg-4    (4 rows, c = R + 16 + (cg-4)*4)
//   cg 8     -> dts rows 0..3
//   cg 9     -> dts rows 4..5
// Each thread covers 2 l's (l0, l0+256). B/C stored CHUNK-INTERLEAVED:
//   float4 index ((bk*8 + i)*4 + j)*256 + t   where l = t*8 + i, j = n/4
// so the scan's step-i read is exactly wave-coalesced (16B lane stride).
// ---------------------------------------------------------------------------
__global__ __launch_bounds__(256) void proj_kernel(
    const float* __restrict__ xs, const float* __restrict__ xpw,
    float4* __restrict__ Bc, float4* __restrict__ Cc,
    float* __restrict__ dts_ws)
{
    __shared__ float sW[4 * D_];
    const int bk = blockIdx.x;
    const int k = bk & 3;
    const int cg = blockIdx.z;
    const int tid = threadIdx.x;

    int c0, nrows;
    if (cg < 8) { c0 = R_ + cg * 4; nrows = 4; }
    else if (cg == 8) { c0 = 0; nrows = 4; }
    else { c0 = 4; nrows = 2; }

    for (int i = tid; i < nrows * D_; i += 256)
        sW[i] = xpw[(k * C_ + c0 + i / D_) * D_ + (i % D_)];
    __syncthreads();

    const int l0 = blockIdx.y * 512 + tid;
    const float* X = xs + (size_t)bk * D_ * L_;

    float acc[4][2];
#pragma unroll
    for (int r = 0; r < 4; ++r) { acc[r][0] = 0.f; acc[r][1] = 0.f; }

#pragma unroll 4
    for (int d = 0; d < D_; ++d) {
        const float x0 = X[d * L_ + l0];
        const float x1 = X[d * L_ + l0 + 256];
#pragma unroll
        for (int r = 0; r < 4; ++r) {
            const float w = sW[r * D_ + d];
            acc[r][0] = fmaf(w, x0, acc[r][0]);
            acc[r][1] = fmaf(w, x1, acc[r][1]);
        }
    }

    if (cg < 8) {
        float4* dst = (cg < 4) ? Bc : Cc;
        const int j = cg & 3;
#pragma unroll
        for (int jj = 0; jj < 2; ++jj) {
            const int l = l0 + jj * 256;
            const int i = l & 7, t = l >> 3;
            dst[(((size_t)bk * 8 + i) * 4 + j) * 256 + t] =
                make_float4(acc[0][jj], acc[1][jj], acc[2][jj], acc[3][jj]);
        }
    } else {
        const int rbase = (cg == 8) ? 0 : 4;
#pragma unroll
        for (int r = 0; r < 4; ++r) {
            if (rbase + r >= R_) break;
#pragma unroll
            for (int jj = 0; jj < 2; ++jj)
                dts_ws[((size_t)bk * R_ + rbase + r) * L_ + l0 + jj * 256] = acc[r][jj];
        }
    }
}

// ---------------------------------------------------------------------------
// Scan: grid B*K*D, block 256; thread owns l in [tid*8, tid*8+8).
// B/C reads are wave-coalesced thanks to the chunk-interleaved layout.
// ---------------------------------------------------------------------------
__global__ __launch_bounds__(256) void scan_kernel(
    const float* __restrict__ xs, const float* __restrict__ A_logs,
    const float* __restrict__ Ds, const float* __restrict__ dtw,
    const float* __restrict__ dtb, const float* __restrict__ dts_ws,
    const float4* __restrict__ Bc, const float4* __restrict__ Cc,
    float* __restrict__ out)
{
    __shared__ float sAw[4][N_];
    __shared__ float sBw[4][N_];

    const int bkd = blockIdx.x;
    const int d = bkd % D_;
    const int bk = bkd / D_;
    const int k = bk & 3;
    const int kd = k * D_ + d;
    const int tid = threadIdx.x;
    const int lane = tid & 63;
    const int wave = tid >> 6;

    // xs chunk -> registers
    const float4* xv4 = (const float4*)(xs + (size_t)bkd * L_);
    const float4 xa = xv4[tid * 2], xb = xv4[tid * 2 + 1];
    float x[8] = {xa.x, xa.y, xa.z, xa.w, xb.x, xb.y, xb.z, xb.w};

    // delta chunk
    float del[8];
    const float bias = dtb[kd];
#pragma unroll
    for (int j = 0; j < 8; ++j) del[j] = bias;
    const float* w2 = dtw + (size_t)kd * R_;
    const float4* dts4 = (const float4*)(dts_ws + (size_t)bk * R_ * L_);
#pragma unroll
    for (int r = 0; r < R_; ++r) {
        const float wr = w2[r];
        const float4 t0 = dts4[r * (L_ / 4) + tid * 2];
        const float4 t1 = dts4[r * (L_ / 4) + tid * 2 + 1];
        del[0] = fmaf(wr, t0.x, del[0]); del[1] = fmaf(wr, t0.y, del[1]);
        del[2] = fmaf(wr, t0.z, del[2]); del[3] = fmaf(wr, t0.w, del[3]);
        del[4] = fmaf(wr, t1.x, del[4]); del[5] = fmaf(wr, t1.y, del[5]);
        del[6] = fmaf(wr, t1.z, del[6]); del[7] = fmaf(wr, t1.w, del[7]);
    }
#pragma unroll
    for (int j = 0; j < 8; ++j) del[j] = softplus_f(del[j]);

    float A[N_];
    const float* Ap = A_logs + (size_t)kd * N_;
#pragma unroll
    for (int n = 0; n < N_; ++n) A[n] = -__expf(Ap[n]);
    const float Dval = Ds[kd];

    const float4* Bv = Bc + (size_t)bk * 8 * 4 * 256;
    const float4* Cv = Cc + (size_t)bk * 8 * 4 * 256;

    // Phase 1: per-chunk aggregate (a, b)
    float a[N_], b[N_];
#pragma unroll
    for (int n = 0; n < N_; ++n) { a[n] = 1.f; b[n] = 0.f; }
#pragma unroll
    for (int i = 0; i < 8; ++i) {
        float Bl[N_];
        *(float4*)&Bl[0]  = Bv[(i * 4 + 0) * 256 + tid];
        *(float4*)&Bl[4]  = Bv[(i * 4 + 1) * 256 + tid];
        *(float4*)&Bl[8]  = Bv[(i * 4 + 2) * 256 + tid];
        *(float4*)&Bl[12] = Bv[(i * 4 + 3) * 256 + tid];
        const float dl = del[i];
        const float dx = dl * x[i];
#pragma unroll
        for (int n = 0; n < N_; ++n) {
            const float dA = __expf(dl * A[n]);
            b[n] = fmaf(dA, b[n], dx * Bl[n]);
            a[n] *= dA;
        }
    }

    // Phase 2a: wave-level inclusive scan
#pragma unroll
    for (int off = 1; off < 64; off <<= 1) {
#pragma unroll
        for (int n = 0; n < N_; ++n) {
            const float pa = __shfl_up(a[n], off, 64);
            const float pb = __shfl_up(b[n], off, 64);
            if (lane >= off) {
                b[n] = fmaf(a[n], pb, b[n]);
                a[n] *= pa;
            }
        }
    }
    // Phase 2b: cross-wave fixup
    if (lane == 63) {
#pragma unroll
        for (int n = 0; n < N_; ++n) { sAw[wave][n] = a[n]; sBw[wave][n] = b[n]; }
    }
    __syncthreads();

    // h at chunk start
    float h[N_];
#pragma unroll
    for (int n = 0; n < N_; ++n) {
        float ae = __shfl_up(a[n], 1, 64);
        float be = __shfl_up(b[n], 1, 64);
        if (lane == 0) { ae = 1.f; be = 0.f; }
        float wb = 0.f;
        for (int w = 0; w < wave; ++w) wb = fmaf(sAw[w][n], wb, sBw[w][n]);
        h[n] = fmaf(ae, wb, be);
    }

    // Phase 3: re-run chunk with true initial state, emit y
    float yv[8];
#pragma unroll
    for (int i = 0; i < 8; ++i) {
        float Bl[N_], Cl[N_];
        *(float4*)&Bl[0]  = Bv[(i * 4 + 0) * 256 + tid];
        *(float4*)&Bl[4]  = Bv[(i * 4 + 1) * 256 + tid];
        *(float4*)&Bl[8]  = Bv[(i * 4 + 2) * 256 + tid];
        *(float4*)&Bl[12] = Bv[(i * 4 + 3) * 256 + tid];
        *(float4*)&Cl[0]  = Cv[(i * 4 + 0) * 256 + tid];
        *(float4*)&Cl[4]  = Cv[(i * 4 + 1) * 256 + tid];
        *(float4*)&Cl[8]  = Cv[(i * 4 + 2) * 256 + tid];
        *(float4*)&Cl[12] = Cv[(i * 4 + 3) * 256 + tid];
        const float dl = del[i];
        const float dx = dl * x[i];
        float y = Dval * x[i];
#pragma unroll
        for (int n = 0; n < N_; ++n) {
            const float dA = __expf(dl * A[n]);
            h[n] = fmaf(dA, h[n], dx * Bl[n]);
            y = fmaf(h[n], Cl[n], y);
        }
        yv[i] = y;
    }
    float4* ov = (float4*)(out + (size_t)bkd * L_);
    ov[tid * 2]     = make_float4(yv[0], yv[1], yv[2], yv[3]);
    ov[tid * 2 + 1] = make_float4(yv[4], yv[5], yv[6], yv[7]);
}

extern "C" void kernel_launch(void* const* d_in, const int* in_sizes, int n_in,
                              void* d_out, int out_size, void* d_ws, size_t ws_size,
                              hipStream_t stream) {
    const float* xs = (const float*)d_in[0];       // (B,K,D,L)
    const float* A_logs = (const float*)d_in[1];   // (K*D, N)
    const float* Ds = (const float*)d_in[2];       // (K*D,)
    const float* dtw = (const float*)d_in[3];      // (K,D,R)
    const float* dtb = (const float*)d_in[4];      // (K,D)
    const float* xpw = (const float*)d_in[5];      // (K,C,D)
    float* out = (float*)d_out;                    // (B,K,D,L) fp32

    float4* Bc = (float4*)d_ws;                              // 16*8*4*256 float4 = 2 MB
    float4* Cc = Bc + (size_t)B_ * K_ * 8 * 4 * 256;         // 2 MB
    float* dts_ws = (float*)(Cc + (size_t)B_ * K_ * 8 * 4 * 256);  // 16*6*2048 floats

    proj_kernel<<<dim3(B_ * K_, 4, 10), 256, 0, stream>>>(xs, xpw, Bc, Cc, dts_ws);
    scan_kernel<<<B_ * K_ * D_, 256, 0, stream>>>(
        xs, A_logs, Ds, dtw, dtb, dts_ws, Bc, Cc, out);
}